// Round 1
// baseline (75.770 us; speedup 1.0000x reference)
//
#include <hip/hip_runtime.h>

namespace {
constexpr int Bn = 32, Dn = 64, Hn = 64, Wn = 64;
constexpr int TH = 4;          // output rows per block
constexpr int DC = 4;          // d-slices staged per barrier pair
constexpr int PLANE = Hn * Wn; // 4096
constexpr float SCALE = 0.125f; // 64^-0.5
}

__global__ __launch_bounds__(256, 2) void dilate_attn_kernel(
    const float* __restrict__ q, const float* __restrict__ k,
    const float* __restrict__ v, float* __restrict__ out)
{
    __shared__ float sk[DC][TH + 2][Wn + 2];

    const int t  = threadIdx.x;
    const int w  = t & 63;
    const int rg = t >> 6;                 // 0..3 : row within tile
    const int b  = blockIdx.x >> 4;
    const int h0 = (blockIdx.x & 15) * TH;
    const int h  = h0 + rg;

    // zero halo columns once (never overwritten afterwards)
    if (t < DC * (TH + 2)) {
        int ds  = t / (TH + 2);
        int row = t - ds * (TH + 2);
        sk[ds][row][0]      = 0.0f;
        sk[ds][row][Wn + 1] = 0.0f;
    }

    // Precompute the 6 staging slots this thread fills each iteration:
    // (ds,row) pairs cover DC * (TH+2) = 24 rows; thread covers rr = rg + i*4.
    int    g_off[6];   // global offset within a d0-chunk, or -1 for padded rows
    float* l_ptr[6];   // LDS destination
#pragma unroll
    for (int i = 0; i < 6; ++i) {
        const int rr  = rg + i * TH;          // 0..23
        const int ds  = rr / (TH + 2);
        const int row = rr - ds * (TH + 2);
        const int hh  = h0 - 1 + row;
        const bool ok = (hh >= 0) && (hh < Hn);
        g_off[i] = ok ? (ds * PLANE + hh * Wn + w) : -1;
        l_ptr[i] = &sk[ds][row][w + 1];
    }

    const int kvbase = b * Dn * PLANE;
    const int qbase  = kvbase + h * Wn + w;

    float attn[9];
#pragma unroll
    for (int i = 0; i < 9; ++i) attn[i] = 0.0f;

    // ---------------- Phase 1: scores = q . k_neighbor over d ----------------
    for (int d0 = 0; d0 < Dn; d0 += DC) {
        const float* kp = k + kvbase + d0 * PLANE;
#pragma unroll
        for (int i = 0; i < 6; ++i)
            *l_ptr[i] = (g_off[i] >= 0) ? kp[g_off[i]] : 0.0f;
        float qv[DC];
#pragma unroll
        for (int ds = 0; ds < DC; ++ds)
            qv[ds] = q[qbase + (d0 + ds) * PLANE];
        __syncthreads();
#pragma unroll
        for (int ds = 0; ds < DC; ++ds)
#pragma unroll
            for (int di = 0; di < 3; ++di)
#pragma unroll
                for (int dj = 0; dj < 3; ++dj)
                    attn[di * 3 + dj] = fmaf(qv[ds], sk[ds][rg + di][w + dj],
                                             attn[di * 3 + dj]);
        __syncthreads();
    }

    // ---------------- softmax over the 9 window positions (in regs) ---------
    // NOTE: zero-padded neighbors legitimately contribute score 0 (reference
    // unfolds with zero padding and does NOT mask), which we reproduce exactly.
#pragma unroll
    for (int i = 0; i < 9; ++i) attn[i] *= SCALE;
    float m = attn[0];
#pragma unroll
    for (int i = 1; i < 9; ++i) m = fmaxf(m, attn[i]);
    float s = 0.0f;
#pragma unroll
    for (int i = 0; i < 9; ++i) { attn[i] = __expf(attn[i] - m); s += attn[i]; }
    const float inv = 1.0f / s;
#pragma unroll
    for (int i = 0; i < 9; ++i) attn[i] *= inv;

    // ---------------- Phase 2: out = sum_n attn_n * v_neighbor --------------
    for (int d0 = 0; d0 < Dn; d0 += DC) {
        const float* vp = v + kvbase + d0 * PLANE;
#pragma unroll
        for (int i = 0; i < 6; ++i)
            *l_ptr[i] = (g_off[i] >= 0) ? vp[g_off[i]] : 0.0f;
        __syncthreads();
#pragma unroll
        for (int ds = 0; ds < DC; ++ds) {
            float acc = 0.0f;
#pragma unroll
            for (int di = 0; di < 3; ++di)
#pragma unroll
                for (int dj = 0; dj < 3; ++dj)
                    acc = fmaf(attn[di * 3 + dj], sk[ds][rg + di][w + dj], acc);
            out[qbase + (d0 + ds) * PLANE] = acc;
        }
        __syncthreads();
    }
}

extern "C" void kernel_launch(void* const* d_in, const int* in_sizes, int n_in,
                              void* d_out, int out_size, void* d_ws, size_t ws_size,
                              hipStream_t stream) {
    const float* q = (const float*)d_in[0];
    const float* k = (const float*)d_in[1];
    const float* v = (const float*)d_in[2];
    float* out = (float*)d_out;
    (void)in_sizes; (void)n_in; (void)out_size; (void)d_ws; (void)ws_size;

    const int grid = Bn * (Hn / TH); // 512 blocks, 2 per CU
    dilate_attn_kernel<<<grid, 256, 0, stream>>>(q, k, v, out);
}

// Round 2
// 31.529 us; speedup vs baseline: 2.4032x; 2.4032x over previous
//
#include <hip/hip_runtime.h>

namespace {
constexpr int Bn = 32, Dn = 64, Hn = 64, Wn = 64;
constexpr int PLANE = Hn * Wn;   // 4096
constexpr int NW  = 4;           // waves per block
constexpr int DPW = Dn / NW;     // 16 d-slices per wave
constexpr float SCALE = 0.125f;  // 64^-0.5
}

__global__ __launch_bounds__(256, 8) void dilate_attn_kernel(
    const float* __restrict__ q, const float* __restrict__ k,
    const float* __restrict__ v, float* __restrict__ out)
{
    __shared__ float red[9][NW][Wn];   // 9216 B

    const int t  = threadIdx.x;
    const int w  = t & 63;
    const int wv = t >> 6;             // wave id 0..3 -> d chunk

    // XCD-chunked swizzle: 2048 blocks, 8 XCDs -> 256 contiguous (b,h) per XCD
    const int bid = blockIdx.x;
    const int swz = (bid & 7) * ((Bn * Hn) >> 3) + (bid >> 3);
    const int b = swz >> 6;
    const int h = swz & 63;

    const int base = b * Dn * PLANE;
    const int pix  = h * Wn + w;

    const bool up_ok = (h > 0), dn_ok = (h < Hn - 1);
    const bool lf_ok = (w > 0), rt_ok = (w < Wn - 1);

    float attn[9];
#pragma unroll
    for (int n = 0; n < 9; ++n) attn[n] = 0.0f;

    // ---------- Phase 1: partial scores over this wave's 16 d-slices --------
    {
        const float* qd = q + base + (wv * DPW) * PLANE + pix;
        const float* kd = k + base + (wv * DPW) * PLANE + pix;
#pragma unroll 4
        for (int ds = 0; ds < DPW; ++ds) {
            const float qv = qd[ds * PLANE];
            const float* kc = kd + ds * PLANE;   // center neighbor address
#pragma unroll
            for (int di = 0; di < 3; ++di) {
                const bool okh = (di == 0) ? up_ok : (di == 2) ? dn_ok : true;
                const int  ro  = (di - 1) * Wn;
#pragma unroll
                for (int dj = 0; dj < 3; ++dj) {
                    const bool okw = (dj == 0) ? lf_ok : (dj == 2) ? rt_ok : true;
                    const float kv = (okh && okw) ? kc[ro + dj - 1] : 0.0f;
                    attn[di * 3 + dj] = fmaf(qv, kv, attn[di * 3 + dj]);
                }
            }
        }
    }

    // ---------- cross-wave reduction of the 9 partial scores ----------------
#pragma unroll
    for (int n = 0; n < 9; ++n) red[n][wv][w] = attn[n];
    __syncthreads();
#pragma unroll
    for (int n = 0; n < 9; ++n)
        attn[n] = (red[n][0][w] + red[n][1][w]) + (red[n][2][w] + red[n][3][w]);

    // ---------- softmax over 9 window positions (zero-pad scores = 0) -------
#pragma unroll
    for (int n = 0; n < 9; ++n) attn[n] *= SCALE;
    float m = attn[0];
#pragma unroll
    for (int n = 1; n < 9; ++n) m = fmaxf(m, attn[n]);
    float s = 0.0f;
#pragma unroll
    for (int n = 0; n < 9; ++n) { attn[n] = __expf(attn[n] - m); s += attn[n]; }
    const float inv = 1.0f / s;
#pragma unroll
    for (int n = 0; n < 9; ++n) attn[n] *= inv;

    // ---------- Phase 2: out = sum_n attn_n * v_neighbor, this wave's d ----
    {
        const float* vd = v + base + (wv * DPW) * PLANE + pix;
        float* od = out + base + (wv * DPW) * PLANE + pix;
#pragma unroll 4
        for (int ds = 0; ds < DPW; ++ds) {
            const float* vc = vd + ds * PLANE;
            float acc = 0.0f;
#pragma unroll
            for (int di = 0; di < 3; ++di) {
                const bool okh = (di == 0) ? up_ok : (di == 2) ? dn_ok : true;
                const int  ro  = (di - 1) * Wn;
#pragma unroll
                for (int dj = 0; dj < 3; ++dj) {
                    const bool okw = (dj == 0) ? lf_ok : (dj == 2) ? rt_ok : true;
                    const float vv = (okh && okw) ? vc[ro + dj - 1] : 0.0f;
                    acc = fmaf(attn[di * 3 + dj], vv, acc);
                }
            }
            od[ds * PLANE] = acc;
        }
    }
}

extern "C" void kernel_launch(void* const* d_in, const int* in_sizes, int n_in,
                              void* d_out, int out_size, void* d_ws, size_t ws_size,
                              hipStream_t stream) {
    const float* q = (const float*)d_in[0];
    const float* k = (const float*)d_in[1];
    const float* v = (const float*)d_in[2];
    float* out = (float*)d_out;
    (void)in_sizes; (void)n_in; (void)out_size; (void)d_ws; (void)ws_size;

    const int grid = Bn * Hn;  // 2048 blocks -> 8 blocks/CU, 32 waves/CU
    dilate_attn_kernel<<<grid, 256, 0, stream>>>(q, k, v, out);
}

// Round 4
// 30.143 us; speedup vs baseline: 2.5137x; 1.0460x over previous
//
#include <hip/hip_runtime.h>

namespace {
constexpr int Bn = 32, Dn = 64, Hn = 64, Wn = 64;
constexpr int PLANE = Hn * Wn;   // 4096
constexpr int NW  = 4;           // waves per block, splitting d
constexpr int DPW = Dn / NW;     // 16 d-slices per wave
constexpr float SCALE = 0.125f;  // 64^-0.5
typedef float f4a __attribute__((ext_vector_type(4), aligned(4)));
}

__global__ __launch_bounds__(256, 4) void dilate_attn_kernel(
    const float* __restrict__ q, const float* __restrict__ k,
    const float* __restrict__ v, float* __restrict__ out)
{
    __shared__ float2 red[NW][9][64];   // 18432 B

    const int t  = threadIdx.x;
    const int l  = t & 63;
    const int wv = t >> 6;              // wave id -> d quarter
    const int ci = l & 31;              // lane col-pair index
    const int lr = l >> 5;              // row within stripe
    const int c  = ci * 2;              // first of this lane's 2 pixel cols

    // XCD-chunked swizzle: 1024 blocks -> 128 contiguous (b,stripe) per XCD
    const int bid = blockIdx.x;
    const int swz = (bid & 7) * 128 + (bid >> 3);
    const int b      = swz >> 5;
    const int stripe = swz & 31;
    const int hr     = stripe * 2 + lr; // this lane's pixel row

    const int  base = b * Dn * PLANE;
    const bool ci0 = (ci == 0), ci31 = (ci == 31);

    // Column base for the 4-wide window load: cols cb..cb+3, always in-row.
    // normal: c-1 (covers c-1..c+2); ci0: 0 (shifted mapping); ci31: c-2.
    const int cb = ci0 ? 0 : (ci31 ? (c - 2) : (c - 1));

    int  koff[3];
    bool rok[3];
#pragma unroll
    for (int di = 0; di < 3; ++di) {
        const int kr = hr - 1 + di;
        rok[di] = (kr >= 0) && (kr < Hn);
        const int krc = min(max(kr, 0), Hn - 1);   // clamped: loads always in-bounds
        koff[di] = krc * Wn + cb;
    }
    const int qoff = hr * Wn + c;

    float a0[9], a1[9];
#pragma unroll
    for (int n = 0; n < 9; ++n) { a0[n] = 0.0f; a1[n] = 0.0f; }

    // -------- Phase 1: partial scores over this wave's 16 d-slices ---------
    {
        const float* kp = k + base + wv * DPW * PLANE;
        const float* qp = q + base + wv * DPW * PLANE;
#pragma unroll 4
        for (int ds = 0; ds < DPW; ++ds) {
            const f4a r0 = *(const f4a*)(kp + koff[0]);
            const f4a r1 = *(const f4a*)(kp + koff[1]);
            const f4a r2 = *(const f4a*)(kp + koff[2]);
            const float2 qv = *(const float2*)(qp + qoff);
            kp += PLANE; qp += PLANE;
#pragma unroll
            for (int di = 0; di < 3; ++di) {
                const f4a vv = (di == 0) ? r0 : (di == 1) ? r1 : r2;
                // window cols c-1..c+2 (don't-care where later zeroed)
                const float w0 = ci31 ? vv.y : vv.x;
                const float w1 = ci0 ? vv.x : (ci31 ? vv.z : vv.y);
                const float w2 = ci0 ? vv.y : (ci31 ? vv.w : vv.z);
                const float w3 = ci0 ? vv.z : vv.w;
                a0[di * 3 + 0] = fmaf(qv.x, w0, a0[di * 3 + 0]);
                a0[di * 3 + 1] = fmaf(qv.x, w1, a0[di * 3 + 1]);
                a0[di * 3 + 2] = fmaf(qv.x, w2, a0[di * 3 + 2]);
                a1[di * 3 + 0] = fmaf(qv.y, w1, a1[di * 3 + 0]);
                a1[di * 3 + 1] = fmaf(qv.y, w2, a1[di * 3 + 1]);
                a1[di * 3 + 2] = fmaf(qv.y, w3, a1[di * 3 + 2]);
            }
        }
    }

    // -------- cross-wave reduction (single barrier) -------------------------
#pragma unroll
    for (int n = 0; n < 9; ++n) red[wv][n][l] = make_float2(a0[n], a1[n]);
    __syncthreads();
#pragma unroll
    for (int n = 0; n < 9; ++n) {
        float2 s = red[0][n][l];
#pragma unroll
        for (int ow = 1; ow < NW; ++ow) {
            const float2 p = red[ow][n][l];
            s.x += p.x; s.y += p.y;
        }
        a0[n] = s.x; a1[n] = s.y;
    }

    // -------- zero invalid-position SCORES (reference: q . 0-pad = 0) -------
#pragma unroll
    for (int di = 0; di < 3; ++di)
#pragma unroll
        for (int dj = 0; dj < 3; ++dj) {
            const int n = di * 3 + dj;
            a0[n] = (rok[di] && (dj != 0 || !ci0))  ? a0[n] : 0.0f;
            a1[n] = (rok[di] && (dj != 2 || !ci31)) ? a1[n] : 0.0f;
        }
#pragma unroll
    for (int n = 0; n < 9; ++n) { a0[n] *= SCALE; a1[n] *= SCALE; }
    float m0 = a0[0], m1 = a1[0];
#pragma unroll
    for (int n = 1; n < 9; ++n) { m0 = fmaxf(m0, a0[n]); m1 = fmaxf(m1, a1[n]); }
    float s0 = 0.0f, s1 = 0.0f;
#pragma unroll
    for (int n = 0; n < 9; ++n) {
        a0[n] = __expf(a0[n] - m0); s0 += a0[n];
        a1[n] = __expf(a1[n] - m1); s1 += a1[n];
    }
    const float i0 = 1.0f / s0, i1 = 1.0f / s1;
#pragma unroll
    for (int n = 0; n < 9; ++n) { a0[n] *= i0; a1[n] *= i1; }

    // -------- zero invalid-position WEIGHTS (reference: attn * v=0 there) ---
    // Denominator above correctly KEPT the exp(0-m) terms; only the multiply
    // against our clamped-address (garbage) v rows/cols must be killed.
#pragma unroll
    for (int di = 0; di < 3; ++di)
#pragma unroll
        for (int dj = 0; dj < 3; ++dj) {
            const int n = di * 3 + dj;
            a0[n] = (rok[di] && (dj != 0 || !ci0))  ? a0[n] : 0.0f;
            a1[n] = (rok[di] && (dj != 2 || !ci31)) ? a1[n] : 0.0f;
        }

    // -------- Phase 2: out = attn . v_window for this wave's d-quarter ------
    {
        const float* vp = v + base + wv * DPW * PLANE;
        float*       op = out + base + wv * DPW * PLANE;
#pragma unroll 4
        for (int ds = 0; ds < DPW; ++ds) {
            const f4a r0 = *(const f4a*)(vp + koff[0]);
            const f4a r1 = *(const f4a*)(vp + koff[1]);
            const f4a r2 = *(const f4a*)(vp + koff[2]);
            vp += PLANE;
            float o0 = 0.0f, o1 = 0.0f;
#pragma unroll
            for (int di = 0; di < 3; ++di) {
                const f4a vv = (di == 0) ? r0 : (di == 1) ? r1 : r2;
                const float w0 = ci31 ? vv.y : vv.x;
                const float w1 = ci0 ? vv.x : (ci31 ? vv.z : vv.y);
                const float w2 = ci0 ? vv.y : (ci31 ? vv.w : vv.z);
                const float w3 = ci0 ? vv.z : vv.w;
                o0 = fmaf(a0[di * 3 + 0], w0, o0);
                o0 = fmaf(a0[di * 3 + 1], w1, o0);
                o0 = fmaf(a0[di * 3 + 2], w2, o0);
                o1 = fmaf(a1[di * 3 + 0], w1, o1);
                o1 = fmaf(a1[di * 3 + 1], w2, o1);
                o1 = fmaf(a1[di * 3 + 2], w3, o1);
            }
            *(float2*)(op + qoff) = make_float2(o0, o1);
            op += PLANE;
        }
    }
}

extern "C" void kernel_launch(void* const* d_in, const int* in_sizes, int n_in,
                              void* d_out, int out_size, void* d_ws, size_t ws_size,
                              hipStream_t stream) {
    const float* q = (const float*)d_in[0];
    const float* k = (const float*)d_in[1];
    const float* v = (const float*)d_in[2];
    float* out = (float*)d_out;
    (void)in_sizes; (void)n_in; (void)out_size; (void)d_ws; (void)ws_size;

    const int grid = Bn * 32;  // 1024 blocks -> 4/CU, 16 waves/CU
    dilate_attn_kernel<<<grid, 256, 0, stream>>>(q, k, v, out);
}